// Round 2
// baseline (77.039 us; speedup 1.0000x reference)
//
#include <hip/hip_runtime.h>
#include <math.h>

// VisualImitation1: the reference's 8 x 1000 x 1000 sign-mask / conv / max
// pipeline collapses analytically:
//   myact = sign (tanhf saturates to exactly +-1.0f for these inputs),
//   mask after {-1,1}->{1,0} map + transpose is a plus-cross with a hole at
//   (ja=floor(z_pos[n,0]*1000), ib=floor(z_pos[n,1]*1000)),
//   the plus-conv reaches 4 only at that center (interior centers only),
//   relu(conv-3) = a single 1.0 pixel per sample n.
// Output I_hat[1000,1000,10] is all zeros except <=8 pixels at
// (ja_n, ib_n, z_cls[n]).
//
// R1 -> R2: fuse the 40 MB zero-fill and the 8-pixel scatter into ONE kernel
// (grid-stride float4 stores; each block computes the <=8 (idx,val) pairs in
// LDS via the faithful tanhf chain, each float4 store cndmask-merges them).
// Saves one dispatch; the remaining ~60 us of dur_us is the harness's 256 MiB
// d_ws poison + 40 MB d_out poison, which sit inside the timed iteration.

#define SIZE 1000
#define NCLS 10
#define MAXN 8

__device__ __forceinline__ float myact(float x) { return tanhf(x * 100000.0f); }

__device__ __forceinline__ float mapped_val(float a, float b, int y, int x) {
    // mask_T[y][x] = myact(y1[x]*x1[y]) * myact(y3[x]*x3[y]); then {-1,1}->{1,0}
    float x1 = myact(a - (float)y);        // gx1 = 0..999
    float x3 = myact(a - (float)(y + 1));  // gx3 = 1..1000
    float y1 = myact(b - (float)(x + 1));  // gy1 = 1..1000
    float y3 = myact(b - (float)x);        // gy3 = 0..999
    float m1 = myact(y1 * x1);
    float m3 = myact(y3 * x3);
    float M  = m1 * m3;
    return (M - 1.0f) * 0.5f * -1.0f;
}

__global__ __launch_bounds__(256) void fill_scatter_kernel(
        const float* __restrict__ z_pos, const int* __restrict__ z_cls,
        float4* __restrict__ out4, int n4, int n) {
    __shared__ int   s_idx[MAXN];
    __shared__ float s_val[MAXN];

    int t = threadIdx.x;
    if (t < MAXN) {
        int   idx = -1;
        float val = 0.0f;
        if (t < n) {
            float a = z_pos[2 * t + 0] * 1000.0f;
            float b = z_pos[2 * t + 1] * 1000.0f;
            int ja = (int)floorf(a);
            int ib = (int)floorf(b);
            // Boundary centers lose a neighbor -> conv<=3 -> relu=0 (SAME pad).
            if (ja >= 1 && ja <= SIZE - 2 && ib >= 1 && ib <= SIZE - 2) {
                float conv = mapped_val(a, b, ja - 1, ib) +
                             mapped_val(a, b, ja + 1, ib) +
                             mapped_val(a, b, ja, ib - 1) +
                             mapped_val(a, b, ja, ib + 1);
                float v = conv - 3.0f;  // relu
                if (v > 0.0f) {
                    idx = (ja * SIZE + ib) * NCLS + z_cls[t];
                    val = v;
                }
            }
        }
        s_idx[t] = idx;
        s_val[t] = val;
    }
    __syncthreads();

    int stride = gridDim.x * blockDim.x;
    for (int i = blockIdx.x * blockDim.x + t; i < n4; i += stride) {
        float4 v = make_float4(0.0f, 0.0f, 0.0f, 0.0f);
        int base = i * 4;
#pragma unroll
        for (int k = 0; k < MAXN; ++k) {
            int d = s_idx[k] - base;     // s_idx==-1 never matches 0..3
            float sv = s_val[k];
            v.x = (d == 0) ? sv : v.x;
            v.y = (d == 1) ? sv : v.y;
            v.z = (d == 2) ? sv : v.z;
            v.w = (d == 3) ? sv : v.w;
        }
        out4[i] = v;
    }
}

extern "C" void kernel_launch(void* const* d_in, const int* in_sizes, int n_in,
                              void* d_out, int out_size, void* d_ws, size_t ws_size,
                              hipStream_t stream) {
    const float* z_pos = (const float*)d_in[0];   // [8,2] float32
    const int* z_cls   = (const int*)d_in[1];     // [8] int32
    float4* out4 = (float4*)d_out;                // [1000,1000,10] f32 = 2.5M float4

    int n = in_sizes[1];                          // number of samples (8)
    if (n > MAXN) n = MAXN;
    int n4 = out_size / 4;                        // 10,000,000 / 4 = 2,500,000

    // 4096 blocks x 256 threads, grid-stride: ~2.4 float4 stores per thread.
    fill_scatter_kernel<<<4096, 256, 0, stream>>>(z_pos, z_cls, out4, n4, n);
}

// Round 3
// 73.228 us; speedup vs baseline: 1.0520x; 1.0520x over previous
//
#include <hip/hip_runtime.h>
#include <math.h>

// VisualImitation1: the reference's 8 x 1000 x 1000 sign-mask / conv / max
// pipeline collapses analytically:
//   myact = sign (tanhf saturates to exactly +-1.0f for these inputs),
//   mask after {-1,1}->{1,0} map + transpose is a plus-cross with a hole at
//   (ja=floor(z_pos[n,0]*1000), ib=floor(z_pos[n,1]*1000)),
//   the plus-conv reaches 4 only at that center (interior centers only),
//   relu(conv-3) = a single 1.0 pixel per sample n.
// Output I_hat[1000,1000,10] is all zeros except <=8 pixels at
// (ja_n, ib_n, z_cls[n]).
//
// R2 -> R3: revert the fill+scatter fusion (R2 was a noise-level regression).
// Structure: rocclr hipMemsetAsync (tuned fill path, ~6.5 us for 40 MB) +
// 8-thread fixup (~2 us). Timed dur_us is dominated by the harness's 256 MiB
// d_ws poison (~43 us) + 40 MB d_out poison (~7 us), which are inside the
// timed iteration and outside kernel control. Kernel-owned portion (~9 us) is
// at the 40 MB store-bandwidth roofline.

#define SIZE 1000
#define NCLS 10

__device__ __forceinline__ float myact(float x) { return tanhf(x * 100000.0f); }

__device__ __forceinline__ float mapped_val(float a, float b, int y, int x) {
    // mask_T[y][x] = myact(y1[x]*x1[y]) * myact(y3[x]*x3[y]); then {-1,1}->{1,0}
    float x1 = myact(a - (float)y);        // gx1 = 0..999
    float x3 = myact(a - (float)(y + 1));  // gx3 = 1..1000
    float y1 = myact(b - (float)(x + 1));  // gy1 = 1..1000
    float y3 = myact(b - (float)x);        // gy3 = 0..999
    float m1 = myact(y1 * x1);
    float m3 = myact(y3 * x3);
    float M  = m1 * m3;
    return (M - 1.0f) * 0.5f * -1.0f;
}

__global__ void fixup_kernel(const float* __restrict__ z_pos,
                             const int* __restrict__ z_cls,
                             float* __restrict__ out, int n) {
    int t = threadIdx.x;
    if (t >= n) return;
    float a = z_pos[2 * t + 0] * 1000.0f;
    float b = z_pos[2 * t + 1] * 1000.0f;
    int ja = (int)floorf(a);
    int ib = (int)floorf(b);
    // Boundary centers lose a neighbor -> conv<=3 -> relu=0 (matches SAME pad).
    if (ja < 1 || ja > SIZE - 2 || ib < 1 || ib > SIZE - 2) return;
    float conv = mapped_val(a, b, ja - 1, ib) + mapped_val(a, b, ja + 1, ib) +
                 mapped_val(a, b, ja, ib - 1) + mapped_val(a, b, ja, ib + 1);
    float val = conv - 3.0f;  // relu
    if (val > 0.0f) {
        int cls = z_cls[t];
        out[(ja * SIZE + ib) * NCLS + cls] = val;
    }
}

extern "C" void kernel_launch(void* const* d_in, const int* in_sizes, int n_in,
                              void* d_out, int out_size, void* d_ws, size_t ws_size,
                              hipStream_t stream) {
    const float* z_pos = (const float*)d_in[0];   // [8,2] float32
    const int* z_cls   = (const int*)d_in[1];     // [8] int32
    float* out = (float*)d_out;                   // [1000,1000,10] float32

    int n = in_sizes[1];  // number of samples (8)

    // Zero the whole output (harness poisons it to 0xAA before every launch).
    hipMemsetAsync(out, 0, (size_t)out_size * sizeof(float), stream);

    // Light up the <=8 nonzero pixels.
    fixup_kernel<<<1, 64, 0, stream>>>(z_pos, z_cls, out, n);
}